// Round 11
// baseline (209.101 us; speedup 1.0000x reference)
//
#include <hip/hip_runtime.h>

#define DF 128
#define SCAN_B 64
#define SCAN_T 256
#define GN 64           // nodes per gather_gemm block
#define MST 272         // LDS mean-row stride bytes (17*16)
#define ECAP 2048       // staged edges per block

typedef __attribute__((ext_vector_type(8))) short short8;
typedef __attribute__((ext_vector_type(4))) float float4v;
typedef __attribute__((ext_vector_type(2))) float floatx2;

__device__ __forceinline__ unsigned int bf16rne(float f) {
    unsigned int u = __float_as_uint(f);
    return (u + 0x7fffu + ((u >> 16) & 1u)) >> 16;
}

__device__ __forceinline__ void dec_add(unsigned int v,
    float& a0, float& a1, float& a2, float& a3) {
    floatx2 f0 = __builtin_amdgcn_cvt_pk_f32_fp8(v, false);
    floatx2 f1 = __builtin_amdgcn_cvt_pk_f32_fp8(v, true);
    a0 += f0.x; a1 += f0.y; a2 += f1.x; a3 += f1.y;
}

// ---------------------------------------------------------------------------
// prep: fused (a) histogram of dst, (b) x fp32 -> bf16 xb AND fp8 xb8,
// (c) [Wl;Wr] swizzle into MFMA B-fragment order (bf16).
// ---------------------------------------------------------------------------
__global__ __launch_bounds__(256) void sage_prep(
    const float* __restrict__ x, const int* __restrict__ dst,
    const float* __restrict__ Wl, const float* __restrict__ Wr,
    int* __restrict__ cnt, char* __restrict__ xb, char* __restrict__ xb8,
    uint4* __restrict__ Bf, int N, int E)
{
    int tid = blockIdx.x * 256 + threadIdx.x;

    if (tid < N * 16) {                      // cast: 16 threads/row, 8 cols each
        int n = tid >> 4;
        int c = (tid & 15) * 8;
        const float4* xp = (const float4*)&x[(size_t)n * DF + c];
        float4 a = xp[0], b = xp[1];
        uint4 o;
        o.x = bf16rne(a.x) | (bf16rne(a.y) << 16);
        o.y = bf16rne(a.z) | (bf16rne(a.w) << 16);
        o.z = bf16rne(b.x) | (bf16rne(b.y) << 16);
        o.w = bf16rne(b.z) | (bf16rne(b.w) << 16);
        *(uint4*)(xb + (size_t)n * 256 + (size_t)(tid & 15) * 16) = o;

        int p0 = __builtin_amdgcn_cvt_pk_fp8_f32(a.x, a.y, 0, false);
        p0     = __builtin_amdgcn_cvt_pk_fp8_f32(a.z, a.w, p0, true);
        int p1 = __builtin_amdgcn_cvt_pk_fp8_f32(b.x, b.y, 0, false);
        p1     = __builtin_amdgcn_cvt_pk_fp8_f32(b.z, b.w, p1, true);
        uint2 o8; o8.x = (unsigned int)p0; o8.y = (unsigned int)p1;
        *(uint2*)(xb8 + (size_t)n * 128 + (size_t)(tid & 15) * 8) = o8;
    }

    if (tid < E) atomicAdd(&cnt[dst[tid]], 1);   // histogram

    if (tid < 4096) {                        // bprep
        int lane = tid & 63;
        int ctks = tid >> 6;
        int ks = ctks >> 3, ct = ctks & 7;
        int q = lane >> 4, m16 = lane & 15;
        int n = ct * 16 + m16;
        unsigned int w[4];
        #pragma unroll
        for (int p = 0; p < 4; ++p) {
            int k0 = ks * 32 + q * 8 + p * 2;
            float f0 = (k0 < DF) ? Wl[k0 * DF + n] : Wr[(k0 - DF) * DF + n];
            float f1 = (k0 + 1 < DF) ? Wl[(k0 + 1) * DF + n] : Wr[(k0 + 1 - DF) * DF + n];
            w[p] = bf16rne(f0) | (bf16rne(f1) << 16);
        }
        uint4 o = {w[0], w[1], w[2], w[3]};
        Bf[tid] = o;
    }
}

// ---------------------------------------------------------------------------
// scan pass 1: per-block reduce -> blktot
// ---------------------------------------------------------------------------
__global__ __launch_bounds__(SCAN_T) void scan_reduce(
    const int* __restrict__ cnt, int* __restrict__ blktot, int N)
{
    __shared__ int sdata[SCAN_T];
    const int t = threadIdx.x, b = blockIdx.x;
    const int chunk = (N + SCAN_B * SCAN_T - 1) / (SCAN_B * SCAN_T);
    const int lo = (b * SCAN_T + t) * chunk;
    const int hi = min(lo + chunk, N);
    int total = 0;
    for (int i = lo; i < hi; ++i) total += cnt[i];
    sdata[t] = total;
    __syncthreads();
    for (int s = SCAN_T / 2; s > 0; s >>= 1) {
        if (t < s) sdata[t] += sdata[t + s];
        __syncthreads();
    }
    if (t == 0) blktot[b] = sdata[0];
}

// ---------------------------------------------------------------------------
// scan pass 2: block-local base + LDS scan + write off/cur
// ---------------------------------------------------------------------------
__global__ __launch_bounds__(SCAN_T) void scan_write(
    int* __restrict__ off, int* __restrict__ cur,
    const int* __restrict__ blktot, int N, int E)
{
    __shared__ int sdata[SCAN_T];
    __shared__ int sbase;
    const int t = threadIdx.x, b = blockIdx.x;
    const int chunk = (N + SCAN_B * SCAN_T - 1) / (SCAN_B * SCAN_T);
    const int lo = (b * SCAN_T + t) * chunk;
    const int hi = min(lo + chunk, N);

    if (t == 0) {
        int s = 0;
        for (int i = 0; i < b; ++i) s += blktot[i];
        sbase = s;
    }
    int total = 0;
    for (int i = lo; i < hi; ++i) total += off[i];
    sdata[t] = total;
    __syncthreads();
    for (int s = 1; s < SCAN_T; s <<= 1) {
        int v = (t >= s) ? sdata[t - s] : 0;
        __syncthreads();
        sdata[t] += v;
        __syncthreads();
    }
    int running = sbase + ((t > 0) ? sdata[t - 1] : 0);
    for (int i = lo; i < hi; ++i) {
        int c = off[i];
        off[i] = running;
        cur[i] = running;
        running += c;
    }
    if (b == 0 && t == 0) off[N] = E;
}

// ---------------------------------------------------------------------------
// counting-sort of src by dst bucket
// ---------------------------------------------------------------------------
__global__ __launch_bounds__(256) void sage_sort(
    const int* __restrict__ src, const int* __restrict__ dst,
    int* __restrict__ cur, int* __restrict__ srt, int E)
{
    int e = blockIdx.x * 256 + threadIdx.x;
    if (e < E) {
        int p = atomicAdd(&cur[dst[e]], 1);
        srt[p] = src[e];
    }
}

// ---------------------------------------------------------------------------
// fused gather + gemm:
//   phase 0: stage block's srt segment + off slice into LDS.
//   phase 1: fp8 gather, 32 lanes/node, 2 nodes/wave. Per node: one
//            predicated batch of min(deg,16) independent loads -> ONE
//            waitcnt -> decode (padding dwords are 0 -> +0.0). Second
//            predicated 8-batch + singles for deg>16. Mean -> LDS bf16.
//   phase 2: MFMA 16x16x32 bf16 (4 waves x 16 nodes x 8 ct)
//   epilogue: out = bf16(x) + relu(C + bl)   (residual from xb, saves
//             the 25.6MB fp32 x stream)
// ---------------------------------------------------------------------------
__global__ __launch_bounds__(256) void sage_gg(
    const char* __restrict__ xb, const char* __restrict__ xb8,
    const int* __restrict__ off, const int* __restrict__ srt,
    const uint4* __restrict__ Bf, const float* __restrict__ bl,
    float* __restrict__ out, int N)
{
    __shared__ char mlds[GN * MST];
    __shared__ int selds[ECAP];
    __shared__ int solds[GN + 1];
    const int t = threadIdx.x;
    const int nb0 = blockIdx.x * GN;
    const int wv = t >> 6;
    const int lane = t & 63;

    // ---- phase 0: stage off-slice and srt segment ----
    const int nend = min(nb0 + GN, N);
    const int nloc = nend - nb0;
    if (t <= nloc) solds[t] = off[nb0 + t];
    const int ebase = off[nb0];
    const int ecnt  = min(off[nend] - ebase, ECAP);
    for (int i = t; i < ecnt; i += 256) selds[i] = srt[ebase + i];
    __syncthreads();

    // ---- phase 1 ----
    {
        const int half = lane >> 5;
        const int ln = lane & 31;
        const size_t lnb = (size_t)ln * 4;

        #pragma unroll
        for (int i = 0; i < GN / 8; ++i) {
            int nl = i * 8 + wv * 2 + half;
            int n = nb0 + nl;
            float a0 = 0.f, a1 = 0.f, a2 = 0.f, a3 = 0.f;
            int deg = 1;
            if (n < N) {
                int start = solds[nl];
                int end   = solds[nl + 1];
                int d     = end - start;
                deg = max(d, 1);

                // batch 1: min(d,16) predicated loads, one wait, decode all
                int K = min(d, 16);
                unsigned int v[16];
                #pragma unroll
                for (int j = 0; j < 16; ++j) {
                    unsigned int val = 0u;
                    if (j < K) {
                        int er = start + j - ebase;
                        int s = (er < ECAP) ? selds[er] : srt[start + j];
                        val = *(const unsigned int*)(xb8 + (size_t)s * 128 + lnb);
                    }
                    v[j] = val;
                }
                #pragma unroll
                for (int j = 0; j < 16; ++j) dec_add(v[j], a0, a1, a2, a3);

                // batch 2: min(rem,8) predicated
                int rem = d - 16;
                if (rem > 0) {
                    int K2 = min(rem, 8);
                    unsigned int w[8];
                    #pragma unroll
                    for (int j = 0; j < 8; ++j) {
                        unsigned int val = 0u;
                        if (j < K2) {
                            int er = start + 16 + j - ebase;
                            int s = (er < ECAP) ? selds[er] : srt[start + 16 + j];
                            val = *(const unsigned int*)(xb8 + (size_t)s * 128 + lnb);
                        }
                        w[j] = val;
                    }
                    #pragma unroll
                    for (int j = 0; j < 8; ++j) dec_add(w[j], a0, a1, a2, a3);

                    // singles for deg > 24 (rare)
                    for (int e = start + 24; e < end; ++e) {
                        int er = e - ebase;
                        int s = (er < ECAP) ? selds[er] : srt[e];
                        unsigned int val = *(const unsigned int*)(xb8 + (size_t)s * 128 + lnb);
                        dec_add(val, a0, a1, a2, a3);
                    }
                }
            }
            float inv = 1.0f / (float)deg;
            uint2 o;
            o.x = bf16rne(a0 * inv) | (bf16rne(a1 * inv) << 16);
            o.y = bf16rne(a2 * inv) | (bf16rne(a3 * inv) << 16);
            *(uint2*)(mlds + nl * MST + ln * 8) = o;
        }
    }
    __syncthreads();

    // ---- phase 2: MFMA (4 waves x 16 nodes x 8 ct) ----
    const int q = lane >> 4, m16 = lane & 15;
    const int nb = nb0 + wv * 16;
    const int am = min(nb + m16, N - 1);
    const short8* arow = (const short8*)(xb + (size_t)am * 256);
    const short8* mrow = (const short8*)(mlds + (wv * 16 + m16) * MST);
    const short8* bfp  = (const short8*)Bf;

    float4v acc[8];
    #pragma unroll
    for (int ct = 0; ct < 8; ++ct) acc[ct] = (float4v){0.f, 0.f, 0.f, 0.f};

    #pragma unroll
    for (int ks = 0; ks < 4; ++ks) {          // mean @ Wl
        short8 af = mrow[ks * 4 + q];
        #pragma unroll
        for (int ct = 0; ct < 8; ++ct) {
            short8 bfrag = bfp[(ks * 8 + ct) * 64 + lane];
            acc[ct] = __builtin_amdgcn_mfma_f32_16x16x32_bf16(af, bfrag, acc[ct], 0, 0, 0);
        }
    }
    #pragma unroll
    for (int ks = 0; ks < 4; ++ks) {          // x @ Wr
        short8 af = arow[ks * 4 + q];
        #pragma unroll
        for (int ct = 0; ct < 8; ++ct) {
            short8 bfrag = bfp[((ks + 4) * 8 + ct) * 64 + lane];
            acc[ct] = __builtin_amdgcn_mfma_f32_16x16x32_bf16(af, bfrag, acc[ct], 0, 0, 0);
        }
    }

    // ---- epilogue: residual from bf16 xb ----
    #pragma unroll
    for (int ct = 0; ct < 8; ++ct) {
        int col = ct * 16 + m16;
        float b = bl[col];
        #pragma unroll
        for (int r = 0; r < 4; ++r) {
            int n2 = nb + q * 4 + r;
            if (n2 < N) {
                unsigned int xu = *(const unsigned short*)(xb + (size_t)n2 * 256 + (size_t)col * 2);
                float xv = __uint_as_float(xu << 16);
                out[(size_t)n2 * DF + col] = xv + fmaxf(acc[ct][r] + b, 0.f);
            }
        }
    }
}

extern "C" void kernel_launch(void* const* d_in, const int* in_sizes, int n_in,
                              void* d_out, int out_size, void* d_ws, size_t ws_size,
                              hipStream_t stream) {
    const float* x  = (const float*)d_in[0];
    const int*   ei = (const int*)d_in[1];
    const float* Wl = (const float*)d_in[2];
    const float* bl = (const float*)d_in[3];
    const float* Wr = (const float*)d_in[4];
    float* out = (float*)d_out;

    const int N = in_sizes[0] / DF;
    const int E = in_sizes[1] / 2;
    const int* src = ei;
    const int* dst = ei + E;

    // ws: off[N+1] | cur[N] | srt[E] | blktot[64] | pad16 | Bf[4096*16B]
    //     | xb[N*256B] | xb8[N*128B]
    int* off    = (int*)d_ws;
    int* cur    = off + (N + 1);
    int* srt    = cur + N;
    int* blktot = srt + E;
    size_t bfoff = ((size_t)(N + 1 + N + E + 64) * 4 + 15) & ~(size_t)15;
    uint4* Bf   = (uint4*)((char*)d_ws + bfoff);
    char* xb    = (char*)d_ws + bfoff + 4096 * 16;
    char* xb8   = xb + (size_t)N * 256;

    hipMemsetAsync(off, 0, (size_t)(N + 1) * sizeof(int), stream);

    int prepT = N * 16;
    sage_prep<<<(prepT + 255) / 256, 256, 0, stream>>>(
        x, dst, Wl, Wr, off, xb, xb8, Bf, N, E);
    scan_reduce<<<SCAN_B, SCAN_T, 0, stream>>>(off, blktot, N);
    scan_write<<<SCAN_B, SCAN_T, 0, stream>>>(off, cur, blktot, N, E);
    sage_sort<<<(E + 255) / 256, 256, 0, stream>>>(src, dst, cur, srt, E);
    sage_gg<<<(N + GN - 1) / GN, 256, 0, stream>>>(
        xb, xb8, off, srt, Bf, bl, out, N);
}